// Round 5
// baseline (6354.565 us; speedup 1.0000x reference)
//
#include <hip/hip_runtime.h>

// SineNet: fc1 -> LSTM(sine) -> proj.  B=64 T=1024 I=128 H=512 4H=2048 NS=32
// Round 5: direct A-fragment loads from LLC-coherent hbuf (no LDS h bounce).
//  - 64 persistent WGs, WG j owns 8 hidden units; W_hh/Wc register B-frags.
//  - hbuf row-major [b][512]f16: MFMA A-frags load directly via
//    global_load_dwordx4 sc0sc1; one vmcnt(0) then 16-MFMA register burst.
//  - Triple-buffered hbuf (t%3); per-(t,wg) flags, relaxed, after store-ack.
//  - Shadow after publish: x staging (even t) / pregate MFMA (odd t) +
//    out-proj partials for out[t-1] via direct h row loads.
//  - 3 barriers + 1 poll per step; no hls => bank-conflict source removed.

constexpr int Bb = 64;
constexpr int Tt = 1024;
constexpr int Ii = 128;
constexpr int Hh = 512;
constexpr int G4 = 2048;
constexpr int NS = 32;
constexpr int NWG = 64;

typedef _Float16 h2 __attribute__((ext_vector_type(2)));
typedef _Float16 h8 __attribute__((ext_vector_type(8)));
typedef float    f4 __attribute__((ext_vector_type(4)));
typedef unsigned int u32;
typedef u32 u32x4 __attribute__((ext_vector_type(4)));

__device__ __forceinline__ float dot8(h8 w, h8 x, float acc) {
  h2 w0 = {w[0], w[1]}, w1 = {w[2], w[3]}, w2 = {w[4], w[5]}, w3 = {w[6], w[7]};
  h2 x0 = {x[0], x[1]}, x1 = {x[2], x[3]}, x2 = {x[4], x[5]}, x3 = {x[6], x[7]};
  acc = __builtin_amdgcn_fdot2(x0, w0, acc, false);
  acc = __builtin_amdgcn_fdot2(x1, w1, acc, false);
  acc = __builtin_amdgcn_fdot2(x2, w2, acc, false);
  acc = __builtin_amdgcn_fdot2(x3, w3, acc, false);
  return acc;
}

__device__ __forceinline__ float sigf(float x) { return 1.f / (1.f + __expf(-x)); }

// ---- Wc = W1@W_ih (fp32) -> f16 B-fragment layout; bias2 = b1@W_ih + b_lstm
__global__ void k_wc(const float* __restrict__ W1, const float* __restrict__ Wih,
                     const float* __restrict__ b1, const float* __restrict__ bl,
                     _Float16* __restrict__ Wc4, float* __restrict__ bias2) {
  const int j = blockIdx.x;   // global gate col 0..2047
  const int i = threadIdx.x;  // k index 0..127
  __shared__ float col[Hh];
  __shared__ float part[128];
  for (int k = i; k < Hh; k += 128) col[k] = Wih[k * G4 + j];
  __syncthreads();
  float s = 0.f;
  for (int k = i; k < Hh; k += 128) s += b1[k] * col[k];
  part[i] = s;
  __syncthreads();
  if (i == 0) {
    float t = bl[j];
    for (int k = 0; k < 128; k++) t += part[k];
    bias2[j] = t;
  }
  float acc = 0.f;
  const float* w1r = W1 + i * Hh;
#pragma unroll 4
  for (int k = 0; k < Hh; k++) acc += w1r[k] * col[k];
  const int gate = j >> 9, jj = (j >> 3) & 63, c8 = j & 7;
  const int cb = 2 * jj + (gate >> 1);
  const int c  = (gate & 1) * 8 + c8;
  const int ks = i >> 5, lane = ((i >> 3) & 3) * 16 + c, e = i & 7;
  Wc4[((cb * 4 + ks) * 64 + lane) * 8 + e] = (_Float16)acc;
}

// ---- W_hh (fp32 [512][2048]) -> f16 B-fragment layout
__global__ void k_whh(const float* __restrict__ W, _Float16* __restrict__ W4) {
  const int id = blockIdx.x * 256 + threadIdx.x;  // < 131072
  const int lane = id & 63, ks = (id >> 6) & 15, cb = id >> 10;
  const int c = lane & 15, q = lane >> 4;
  const int jj = cb >> 1, gp = cb & 1;
  const int gate = gp * 2 + (c >> 3);
  const int col = gate * 512 + jj * 8 + (c & 7);
  h8 o;
#pragma unroll
  for (int e = 0; e < 8; ++e) o[e] = (_Float16)W[(ks * 32 + q * 8 + e) * G4 + col];
  *(h8*)(W4 + ((cb * 16 + ks) * 64 + lane) * 8) = o;
}

// ---- persistent scan ------------------------------------------------------
__global__ __launch_bounds__(512, 1) void k_scan(
    const float* __restrict__ x, const _Float16* __restrict__ Wc4,
    const float* __restrict__ bias2, const _Float16* __restrict__ Whh4,
    const float* __restrict__ Wo, const float* __restrict__ bo,
    float* __restrict__ out, u32* __restrict__ hbuf, int* __restrict__ flags) {
  const int j = blockIdx.x;
  const int tid = threadIdx.x;
  const int lane = tid & 63, wv = tid >> 6;
  const int mt = wv >> 1, nt = wv & 1;
  const int cb = 2 * j + nt;
  const int l15 = lane & 15, l4 = lane >> 4;

  __shared__ __align__(16) char xws[32768];   // x window [128][128] f16, swizzled
  __shared__ __align__(16) char wots[32768];  // Wo^T [32][512] f16, swizzled
  __shared__ float pre_s[2][64][33];          // pregates (padded)
  __shared__ float gat_s[64][33];             // h@Whh result (padded)
  __shared__ __align__(16) u32 hxs[256];      // packed new-h [64 b][8 f16]
  __shared__ float op_s[32][17];              // out-proj partials

  h8 bW[16], bC[4];
#pragma unroll
  for (int ks = 0; ks < 16; ++ks)
    bW[ks] = *(const h8*)(Whh4 + ((cb * 16 + ks) * 64 + lane) * 8);
#pragma unroll
  for (int ks = 0; ks < 4; ++ks)
    bC[ks] = *(const h8*)(Wc4 + ((cb * 4 + ks) * 64 + lane) * 8);

  const int b8 = tid >> 3, ml = tid & 7;
  const float bI = bias2[j * 8 + ml],        bF = bias2[512 + j * 8 + ml],
              bG = bias2[1024 + j * 8 + ml], bO = bias2[1536 + j * 8 + ml];
  const int nn = tid & 31, pp = tid >> 5;
  const float bor = (tid < NS) ? bo[tid] : 0.f;

  // stage Wo^T (f16, swizzled)
  for (int it = tid; it < Hh * NS; it += 512) {
    int k = it >> 5, n = it & 31;
    *(_Float16*)(wots + n * 1024 + ((2 * k) ^ ((n & 7) << 4))) = (_Float16)Wo[k * NS + n];
  }
  float c_ = 0.f;

  auto stage_x = [&](int t0) {  // stage steps {t0, t0+1}
#pragma unroll
    for (int q = 0; q < 4; ++q) {
      int n = q * 512 + tid;
      int row = n >> 4, cc = n & 15;
      int b2 = row & 63, tt2 = row >> 6;
      const float* src = x + ((size_t)b2 * Tt + (t0 + tt2)) * Ii + cc * 8;
      f4 s0 = *(const f4*)src, s1 = *(const f4*)(src + 4);
      h8 v = {(_Float16)s0[0], (_Float16)s0[1], (_Float16)s0[2], (_Float16)s0[3],
              (_Float16)s1[0], (_Float16)s1[1], (_Float16)s1[2], (_Float16)s1[3]};
      *(h8*)(xws + row * 256 + ((cc * 16) ^ ((row & 7) << 4))) = v;
    }
  };
  auto do_pregate = [&]() {  // pre_s[0/1] for the 2 staged steps
#pragma unroll
    for (int r2 = 0; r2 < 2; ++r2) {
      const int rt = (wv >> 1) + r2 * 4;
      f4 pa = {0.f, 0.f, 0.f, 0.f};
#pragma unroll
      for (int ks = 0; ks < 4; ++ks) {
        const int row = rt * 16 + l15;
        h8 a = *(const h8*)(xws + row * 256 + ((ks * 64 + l4 * 16) ^ ((row & 7) << 4)));
        pa = __builtin_amdgcn_mfma_f32_16x16x32_f16(a, bC[ks], pa, 0, 0, 0);
      }
#pragma unroll
      for (int e = 0; e < 4; ++e)
        pre_s[rt >> 2][(rt & 3) * 16 + l4 * 4 + e][nt * 16 + l15] = pa[e];
    }
  };
  auto outproj_part = [&](const u32* hrow) {  // partials of h[row j] @ Wo
    u32x4 hv4[4];
#pragma unroll
    for (int q = 0; q < 4; ++q) {
      const u32* p = hrow + pp * 16 + q * 4;
      asm volatile("global_load_dwordx4 %0, %1, off sc0 sc1" : "=v"(hv4[q]) : "v"(p));
    }
    asm volatile("s_waitcnt vmcnt(0)" ::: "memory");
    __builtin_amdgcn_sched_barrier(0);
    float acc = 0.f;
#pragma unroll
    for (int q = 0; q < 4; ++q) {
      h8 wv_ = *(const h8*)(wots + nn * 1024 + ((pp * 64 + q * 16) ^ ((nn & 7) << 4)));
      acc = dot8(wv_, __builtin_bit_cast(h8, hv4[q]), acc);
    }
    op_s[nn][pp] = acc;
  };

  stage_x(0);
  __syncthreads();
  do_pregate();  // pre for steps 0,1

  const int abase = (mt * 16 + l15) * 1024 + l4 * 16;  // A-frag byte base

#pragma unroll 1
  for (int t = 0; t < Tt; ++t) {
    const int tph = t & 1;
    u32* const hcur  = hbuf + (t % 3) * 16384;
    const u32* const hprev = hbuf + ((t + 2) % 3) * 16384;
    // gate GEMM: gat_s[64][32] = h_{t-1} @ W_hh (K=512), A direct from LLC
    if (t == 0) {
#pragma unroll
      for (int e = 0; e < 4; ++e)
        gat_s[mt * 16 + l4 * 4 + e][nt * 16 + l15] = 0.f;
    } else {
      u32x4 a[16];
      const char* ap = (const char*)hprev + abase;
#pragma unroll
      for (int ks = 0; ks < 16; ++ks) {
        const char* p = ap + ks * 64;
        asm volatile("global_load_dwordx4 %0, %1, off sc0 sc1" : "=v"(a[ks]) : "v"(p));
      }
      asm volatile("s_waitcnt vmcnt(0)" ::: "memory");
      __builtin_amdgcn_sched_barrier(0);
      f4 g0 = {0.f, 0.f, 0.f, 0.f}, g1 = {0.f, 0.f, 0.f, 0.f};
#pragma unroll
      for (int ks = 0; ks < 16; ++ks) {
        h8 av = __builtin_bit_cast(h8, a[ks]);
        if (ks & 1) g1 = __builtin_amdgcn_mfma_f32_16x16x32_f16(av, bW[ks], g1, 0, 0, 0);
        else        g0 = __builtin_amdgcn_mfma_f32_16x16x32_f16(av, bW[ks], g0, 0, 0, 0);
      }
#pragma unroll
      for (int e = 0; e < 4; ++e)
        gat_s[mt * 16 + l4 * 4 + e][nt * 16 + l15] = g0[e] + g1[e];
    }
    __syncthreads();  // B1: gat_s ready
    // cell update -> hxs
    {
      float aI = gat_s[b8][ml]      + pre_s[tph][b8][ml]      + bI;
      float aF = gat_s[b8][8 + ml]  + pre_s[tph][b8][8 + ml]  + bF;
      float aG = gat_s[b8][16 + ml] + pre_s[tph][b8][16 + ml] + bG;
      float aO = gat_s[b8][24 + ml] + pre_s[tph][b8][24 + ml] + bO;
      float iv = sigf(aI), fv = sigf(aF), gv = __sinf(aG), ov = sigf(aO);
      c_ = fv * c_ + iv * gv;
      float hn = ov * __sinf(c_);
      ((_Float16*)hxs)[tid] = (_Float16)hn;
    }
    __syncthreads();  // B2: hxs ready
    // publish (wave 7): 16B coherent store per batch row, ack, flag
    if (tid >= 448) {
      const int b = tid & 63;
      u32x4 v = *(const u32x4*)((const char*)hxs + b * 16);
      u32* dst = hcur + b * 256 + j * 4;
      asm volatile("global_store_dwordx4 %0, %1, off sc0 sc1" :: "v"(dst), "v"(v) : "memory");
      asm volatile("s_waitcnt vmcnt(0)" ::: "memory");
      if (tid == 448)
        __hip_atomic_store(&flags[t * NWG + j], 1, __ATOMIC_RELAXED, __HIP_MEMORY_SCOPE_AGENT);
    }
    // ---- shadow work ----
    if (tph == 0) { if (t <= 1020) stage_x(t + 2); }
    else if (t <= 1021) do_pregate();
    if (t > 0) outproj_part(hprev + j * 256);  // partials for out[t-1]
    // poll (wave 0)
    if (tid < NWG) {
      while (!__hip_atomic_load(&flags[t * NWG + tid], __ATOMIC_RELAXED,
                                __HIP_MEMORY_SCOPE_AGENT))
        __builtin_amdgcn_s_sleep(1);
    }
    __syncthreads();  // B_top: h_t published everywhere; op_s ready
    if (t > 0 && tid < NS) {
      float s = bor;
#pragma unroll
      for (int p = 0; p < 16; ++p) s += op_s[tid][p];
      out[((size_t)j * Tt + (t - 1)) * NS + tid] = s;
    }
  }
  // epilogue: out[1023] from h_{1023} in hbuf[(Tt-1)%3]
  outproj_part(hbuf + ((Tt - 1) % 3) * 16384 + j * 256);
  __syncthreads();
  if (tid < NS) {
    float s = bor;
#pragma unroll
    for (int p = 0; p < 16; ++p) s += op_s[tid][p];
    out[((size_t)j * Tt + 1023) * NS + tid] = s;
  }
}

extern "C" void kernel_launch(void* const* d_in, const int* in_sizes, int n_in,
                              void* d_out, int out_size, void* d_ws, size_t ws_size,
                              hipStream_t stream) {
  const float* x   = (const float*)d_in[0];
  const float* W1  = (const float*)d_in[1];
  const float* b1  = (const float*)d_in[2];
  const float* Wih = (const float*)d_in[3];
  const float* Whh = (const float*)d_in[4];
  const float* bl  = (const float*)d_in[5];
  const float* Wo  = (const float*)d_in[6];
  const float* bo  = (const float*)d_in[7];
  float* out = (float*)d_out;

  char* ws = (char*)d_ws;
  _Float16* Wc4   = (_Float16*)(ws);                 // 512 KB
  float*    bias2 = (float*)(ws + 524288);           // 8 KB
  _Float16* Whh4  = (_Float16*)(ws + 532480);        // 2 MB
  u32*      hbuf  = (u32*)(ws + 2629632);            // 192 KB (triple buffer)
  int*      flags = (int*)(ws + 2826240);            // 256 KB (per-(t,wg) slots)

  (void)hipMemsetAsync(flags, 0, Tt * NWG * sizeof(int), stream);
  k_wc<<<G4, 128, 0, stream>>>(W1, Wih, b1, bl, Wc4, bias2);
  k_whh<<<512, 256, 0, stream>>>(Whh, Whh4);
  k_scan<<<NWG, 512, 0, stream>>>(x, Wc4, bias2, Whh4, Wo, bo, out, hbuf, flags);
}

// Round 8
// 3112.152 us; speedup vs baseline: 2.0419x; 2.0419x over previous
//
#include <hip/hip_runtime.h>

// SineNet: fc1 -> LSTM(sine) -> proj.  B=64 T=1024 I=128 H=512 4H=2048 NS=32
// Round 8: 16 gangs x 16 WGs with the UNMODIFIED R4-proven sync protocol.
//  - NO XCC_ID reads, NO adaptive paths, NO epoch rings (R6/R7 hang suspects).
//  - Flags: write-once per (t, gang, member), __hip_atomic_store/load
//    RELAXED+AGENT (exact R4 mechanism). Data: sc0 sc1 (LLC-coherent).
//  - Gang g = blockIdx>>4 owns batches [4g,4g+4); WG ss = blockIdx&15 owns
//    units [32ss,32ss+32) = 128 gate cols; W_hh (64KB) + Wc (16KB) in VGPRs,
//    N-split across 8 waves (wave wv: 16 cols), K=512 -> 16 MFMA/wave/step.
//  - Per step: publish 256B, poll 16 flags (1 line), restage 4KB h.
//  - Shadow between publish and poll: x staging (even t) / pregate (odd t)
//    + out-proj partials. 4 barriers + 1 poll per step.

constexpr int Bb = 64;
constexpr int Tt = 1024;
constexpr int Ii = 128;
constexpr int Hh = 512;
constexpr int G4 = 2048;
constexpr int NS = 32;
constexpr int NG = 16;   // gangs
constexpr int GW = 16;   // WGs per gang
constexpr int BPG = 4;   // batches per gang

typedef _Float16 h2 __attribute__((ext_vector_type(2)));
typedef _Float16 h8 __attribute__((ext_vector_type(8)));
typedef float    f4 __attribute__((ext_vector_type(4)));
typedef unsigned int u32;
typedef u32 u32x4 __attribute__((ext_vector_type(4)));

__device__ __forceinline__ float dot8(h8 w, h8 x, float acc) {
  h2 w0 = {w[0], w[1]}, w1 = {w[2], w[3]}, w2 = {w[4], w[5]}, w3 = {w[6], w[7]};
  h2 x0 = {x[0], x[1]}, x1 = {x[2], x[3]}, x2 = {x[4], x[5]}, x3 = {x[6], x[7]};
  acc = __builtin_amdgcn_fdot2(x0, w0, acc, false);
  acc = __builtin_amdgcn_fdot2(x1, w1, acc, false);
  acc = __builtin_amdgcn_fdot2(x2, w2, acc, false);
  acc = __builtin_amdgcn_fdot2(x3, w3, acc, false);
  return acc;
}

__device__ __forceinline__ float sigf(float x) { return 1.f / (1.f + __expf(-x)); }

// WG ss owns units [32ss,32ss+32). Per-WG col c128 = gate*32+u (0..127);
// col-block cb = c128>>4 (one per wave); global col = gate*512 + ss*32 + u.

// ---- Wc = W1@W_ih (fp32) -> f16 B-frags; bias2 = b1@W_ih + b_lstm ---------
__global__ void k_wc(const float* __restrict__ W1, const float* __restrict__ Wih,
                     const float* __restrict__ b1, const float* __restrict__ bl,
                     _Float16* __restrict__ Wc4, float* __restrict__ bias2) {
  const int j = blockIdx.x;   // global gate col 0..2047
  const int i = threadIdx.x;  // k index 0..127
  __shared__ float col[Hh];
  __shared__ float part[128];
  for (int k = i; k < Hh; k += 128) col[k] = Wih[k * G4 + j];
  __syncthreads();
  float s = 0.f;
  for (int k = i; k < Hh; k += 128) s += b1[k] * col[k];
  part[i] = s;
  __syncthreads();
  if (i == 0) {
    float t = bl[j];
    for (int k = 0; k < 128; k++) t += part[k];
    bias2[j] = t;
  }
  float acc = 0.f;
  const float* w1r = W1 + i * Hh;
#pragma unroll 4
  for (int k = 0; k < Hh; k++) acc += w1r[k] * col[k];
  const int gate = j >> 9, r = j & 511, ss = r >> 5, u = r & 31;
  const int c128 = gate * 32 + u, cb = c128 >> 4, c = c128 & 15;
  const int lane = ((i >> 3) & 3) * 16 + c, ks4 = i >> 5, e = i & 7;
  Wc4[((ss * 8 + cb) * 4 + ks4) * 512 + lane * 8 + e] = (_Float16)acc;
}

// ---- W_hh (fp32 [512][2048]) -> f16 B-frags -------------------------------
__global__ void k_whh(const float* __restrict__ W, _Float16* __restrict__ W4) {
  const int id = blockIdx.x * 256 + threadIdx.x;  // < 131072
  const int lane = id & 63, ks = (id >> 6) & 15, cb = (id >> 10) & 7, ss = id >> 13;
  const int c = lane & 15, c128 = cb * 16 + c;
  const int gate = c128 >> 5, u = c128 & 31;
  const int colg = gate * 512 + ss * 32 + u;
  h8 o;
#pragma unroll
  for (int e = 0; e < 8; ++e)
    o[e] = (_Float16)W[(ks * 32 + (lane >> 4) * 8 + e) * G4 + colg];
  *(h8*)(W4 + ((ss * 8 + cb) * 16 + ks) * 512 + lane * 8) = o;
}

// ---- persistent scan: 256 WGs = 16 gangs of 16 ----------------------------
__global__ __launch_bounds__(512, 1) void k_scan(
    const float* __restrict__ x, const _Float16* __restrict__ Wc4,
    const float* __restrict__ bias2, const _Float16* __restrict__ Whh4,
    const float* __restrict__ Wo, const float* __restrict__ bo,
    float* __restrict__ out, char* __restrict__ hpub, int* __restrict__ flags) {
  const int gid = blockIdx.x >> 4, ss = blockIdx.x & 15;
  const int tid = threadIdx.x;
  const int lane = tid & 63, wv = tid >> 6;
  const int l15 = lane & 15, l4 = lane >> 4;

  __shared__ __align__(16) char hls[16384];   // h [16 rows][512] f16 swizzled (rows 0-3 live, 4-15 zero)
  __shared__ __align__(16) char xws[4096];    // x window [8 rows][128] f16 swizzled (+pad rows)
  __shared__ __align__(16) char wots[32768];  // Wo^T [32][512] f16 swizzled
  __shared__ float pre_s[2][2][4][4][33];     // [buf][tt][b][gate][u]
  __shared__ float gat_s[4][4][33];           // [b][gate][u]
  __shared__ float op_s[32][17];
  __shared__ __align__(16) char hxs[256];     // new h [4 b][32 u] f16

  // ---- register weights: wave wv owns col-block cb = wv --------------------
  h8 bW[16], bC[4];
#pragma unroll
  for (int ks = 0; ks < 16; ++ks)
    bW[ks] = *(const h8*)(Whh4 + ((ss * 8 + wv) * 16 + ks) * 512 + lane * 8);
#pragma unroll
  for (int ks = 0; ks < 4; ++ks)
    bC[ks] = *(const h8*)(Wc4 + ((ss * 8 + wv) * 4 + ks) * 512 + lane * 8);

  const int b8 = tid >> 5, ml = tid & 31;  // cell role (tid<128): batch, unit
  const float bI = bias2[ss * 32 + ml],        bF = bias2[512 + ss * 32 + ml],
              bG = bias2[1024 + ss * 32 + ml], bO = bias2[1536 + ss * 32 + ml];
  const int nn = tid & 31, pp = tid >> 5;  // out-proj role
  const float bor = (tid < NS) ? bo[tid] : 0.f;

  // ---- init LDS: zero hls + xws, stage Wo^T --------------------------------
#pragma unroll
  for (int q = 0; q < 2; ++q) {
    u32x4 z = {0, 0, 0, 0};
    *(u32x4*)(hls + (q * 512 + tid) * 16) = z;
  }
  if (tid < 256) { u32x4 z = {0, 0, 0, 0}; *(u32x4*)(xws + tid * 16) = z; }
  for (int it = tid; it < Hh * NS; it += 512) {
    int k = it >> 5, n = it & 31;
    *(_Float16*)(wots + n * 1024 + ((2 * k) ^ ((n & 7) << 4))) = (_Float16)Wo[k * NS + n];
  }
  float c_ = 0.f;

  auto stage_x = [&](int t0) {  // rows tt*4+b of [8][128] f16
    if (tid < 128) {
      const int row = tid >> 4, cc = tid & 15;
      const float* src = x + ((size_t)(gid * BPG + (row & 3)) * Tt + t0 + (row >> 2)) * Ii + cc * 8;
      f4 s0 = *(const f4*)src, s1 = *(const f4*)(src + 4);
      h8 v = {(_Float16)s0[0], (_Float16)s0[1], (_Float16)s0[2], (_Float16)s0[3],
              (_Float16)s1[0], (_Float16)s1[1], (_Float16)s1[2], (_Float16)s1[3]};
      *(h8*)(xws + row * 256 + ((cc * 16) ^ ((row & 7) << 4))) = v;
    }
  };
  auto do_pregate = [&](int buf) {  // wave wv: its 16 cols; C rows 0-7 used
    f4 pa = {0.f, 0.f, 0.f, 0.f};
#pragma unroll
    for (int ks = 0; ks < 4; ++ks) {
      const int row = l15;
      h8 a = (row < 8)
        ? *(const h8*)(xws + row * 256 + ((ks * 64 + l4 * 16) ^ ((row & 7) << 4)))
        : h8{};
      pa = __builtin_amdgcn_mfma_f32_16x16x32_f16(a, bC[ks], pa, 0, 0, 0);
    }
    if (l4 < 2) {
      const int c128 = wv * 16 + l15, gam = c128 >> 5, u = c128 & 31;
#pragma unroll
      for (int e = 0; e < 4; ++e) {
        const int row = l4 * 4 + e;  // 0..7 = tt*4 + b
        pre_s[buf][row >> 2][row & 3][gam][u] = pa[e];
      }
    }
  };
  auto op_part = [&]() {  // WGs ss<4: partials of h[row ss] @ Wo (from hls)
    if (ss < BPG) {
      float acc = 0.f;
#pragma unroll
      for (int q = 0; q < 4; ++q) {
        h8 w_ = *(const h8*)(wots + nn * 1024 + ((pp * 64 + q * 16) ^ ((nn & 7) << 4)));
        h8 hv = *(const h8*)(hls + ss * 1024 + ((pp * 64 + q * 16) ^ ((ss & 7) << 4)));
        acc = dot8(w_, hv, acc);
      }
      op_s[nn][pp] = acc;
    }
  };

  stage_x(0);
  __syncthreads();
  do_pregate(0);  // steps 0,1

#pragma unroll 1
  for (int t = 0; t < Tt; ++t) {
    char* const hpg = hpub + gid * 8192 + (t & 1) * 4096;
    // ---- gate GEMM: wave wv computes its 16 cols, K=512 -------------------
    {
      f4 g0 = {0.f, 0.f, 0.f, 0.f}, g1 = {0.f, 0.f, 0.f, 0.f};
#pragma unroll
      for (int ks = 0; ks < 16; ++ks) {
        const int row = l15;
        h8 a = *(const h8*)(hls + row * 1024 + ((ks * 64 + l4 * 16) ^ ((row & 7) << 4)));
        if (ks & 1) g1 = __builtin_amdgcn_mfma_f32_16x16x32_f16(a, bW[ks], g1, 0, 0, 0);
        else        g0 = __builtin_amdgcn_mfma_f32_16x16x32_f16(a, bW[ks], g0, 0, 0, 0);
      }
      if (l4 == 0) {
        const int c128 = wv * 16 + l15, gam = c128 >> 5, u = c128 & 31;
#pragma unroll
        for (int e = 0; e < 4; ++e) gat_s[e][gam][u] = g0[e] + g1[e];
      }
    }
    __syncthreads();  // B1: gat_s ready
    // ---- cell update -> hxs ----------------------------------------------
    if (tid < 128) {
      const int ph = (t >> 1) & 1, tt = t & 1;
      float aI = gat_s[b8][0][ml] + pre_s[ph][tt][b8][0][ml] + bI;
      float aF = gat_s[b8][1][ml] + pre_s[ph][tt][b8][1][ml] + bF;
      float aG = gat_s[b8][2][ml] + pre_s[ph][tt][b8][2][ml] + bG;
      float aO = gat_s[b8][3][ml] + pre_s[ph][tt][b8][3][ml] + bO;
      float iv = sigf(aI), fv = sigf(aF), gv = __sinf(aG), ov = sigf(aO);
      c_ = fv * c_ + iv * gv;
      float hn = ov * __sinf(c_);
      ((_Float16*)hxs)[tid] = (_Float16)hn;  // [b8][ml]
    }
    __syncthreads();  // B2: hxs ready
    // ---- publish (wave 7): 256B slice, ack, write-once flag ---------------
    if (tid >= 448 && tid < 464) {
      const int k = tid - 448, b = k >> 2, q = k & 3;
      u32x4 v = *(const u32x4*)(hxs + b * 64 + q * 16);
      char* dst = hpg + b * 1024 + ss * 64 + q * 16;
      asm volatile("global_store_dwordx4 %0, %1, off sc0 sc1" :: "v"(dst), "v"(v) : "memory");
    }
    if (wv == 7) asm volatile("s_waitcnt vmcnt(0)" ::: "memory");
    if (tid == 448)
      __hip_atomic_store(&flags[(t * NG + gid) * GW + ss], 1,
                         __ATOMIC_RELAXED, __HIP_MEMORY_SCOPE_AGENT);
    // ---- shadow (no remote deps) -----------------------------------------
    if (!(t & 1)) { if (t <= 1020) stage_x(t + 2); }
    else if (t <= 1021) do_pregate(((t + 1) >> 1) & 1);
    if (t > 0) op_part();
    // ---- poll own gang's 16 flags (R4 form) -------------------------------
    if (tid < GW) {
      while (!__hip_atomic_load(&flags[(t * NG + gid) * GW + tid],
                                __ATOMIC_RELAXED, __HIP_MEMORY_SCOPE_AGENT))
        __builtin_amdgcn_s_sleep(1);
    }
    __syncthreads();  // B3: h_t published; op_s ready; hls readers done
    if (t > 0 && ss < BPG && tid < NS) {
      float s_ = bor;
#pragma unroll
      for (int p = 0; p < 16; ++p) s_ += op_s[tid][p];
      out[((size_t)(gid * BPG + ss) * Tt + (t - 1)) * NS + tid] = s_;
    }
    // ---- restage h_t (4KB) into hls rows 0-3 ------------------------------
    if (tid < 256) {
      const int b = tid >> 6, cc = tid & 63;
      const char* sp = hpg + b * 1024 + cc * 16;
      u32x4 v;
      asm volatile("global_load_dwordx4 %0, %1, off sc0 sc1\ns_waitcnt vmcnt(0)"
                   : "=v"(v) : "v"(sp) : "memory");
      __builtin_amdgcn_sched_barrier(0);
      *(u32x4*)(hls + b * 1024 + ((cc * 16) ^ ((b & 7) << 4))) = v;
    }
    __syncthreads();  // B4: hls = h_t
  }
  // epilogue: out[1023]
  op_part();
  __syncthreads();
  if (ss < BPG && tid < NS) {
    float s_ = bor;
#pragma unroll
    for (int p = 0; p < 16; ++p) s_ += op_s[tid][p];
    out[((size_t)(gid * BPG + ss) * Tt + 1023) * NS + tid] = s_;
  }
}

extern "C" void kernel_launch(void* const* d_in, const int* in_sizes, int n_in,
                              void* d_out, int out_size, void* d_ws, size_t ws_size,
                              hipStream_t stream) {
  const float* x   = (const float*)d_in[0];
  const float* W1  = (const float*)d_in[1];
  const float* b1  = (const float*)d_in[2];
  const float* Wih = (const float*)d_in[3];
  const float* Whh = (const float*)d_in[4];
  const float* bl  = (const float*)d_in[5];
  const float* Wo  = (const float*)d_in[6];
  const float* bo  = (const float*)d_in[7];
  float* out = (float*)d_out;

  char* ws = (char*)d_ws;
  _Float16* Wc4   = (_Float16*)(ws);            // 512 KB
  float*    bias2 = (float*)(ws + 524288);      // 8 KB
  _Float16* Whh4  = (_Float16*)(ws + 532480);   // 2 MB
  char*     hpub  = ws + 2629632;               // 128 KB (16 gangs x 2 x 4KB)
  int*      flags = (int*)(ws + 2760704);       // 1 MB  (1024 t x 16 gangs x 16)

  (void)hipMemsetAsync(flags, 0, Tt * NG * GW * sizeof(int), stream);
  k_wc<<<G4, 128, 0, stream>>>(W1, Wih, b1, bl, Wc4, bias2);
  k_whh<<<512, 256, 0, stream>>>(Whh, Whh4);
  k_scan<<<256, 512, 0, stream>>>(x, Wc4, bias2, Whh4, Wo, bo, out, hpub, flags);
}

// Round 9
// 1906.270 us; speedup vs baseline: 3.3335x; 1.6326x over previous
//
#include <hip/hip_runtime.h>

// SineNet: fc1 -> LSTM(sine) -> proj.  B=64 T=1024 I=128 H=512 4H=2048 NS=32
// Round 9: tagged-packet h exchange (no acks, no flags) + 2-barrier step.
//  - 16 gangs x 16 WGs (gang = bid>>4, placement-independent), 4 batches/gang.
//  - h published as per-unit dword packets {f16 h | (t+1)<<16} via sc0 sc1:
//    a 4B store is atomic, so packet is self-validating -> publisher issues
//    1 store/thread (cell phase) with NO vmcnt ack and NO flag store.
//  - Readers poll their own 4 packets (one dwordx4) until all tags == t+1,
//    then ds_write_b64 into double-buffered hls. Ring depth 2 is skew-safe:
//    slot(t) overwritten at t+2 only after all members consumed t.
//  - Replay safety: hpub memset to 0 every launch (stale tags == t+1 from a
//    previous replay would otherwise be accepted).
//  - Barriers: B1 (gat_s), B3 (ds_write <-> next GEMM ds_read). hxs/B2/B4
//    eliminated. hls swizzle widened to full (row<<4).
//  - W_hh (64KB) + Wc (16KB) per WG in VGPRs (B-frags), N-split on 8 waves.

constexpr int Bb = 64;
constexpr int Tt = 1024;
constexpr int Ii = 128;
constexpr int Hh = 512;
constexpr int G4 = 2048;
constexpr int NS = 32;
constexpr int NG = 16;   // gangs
constexpr int GW = 16;   // WGs per gang
constexpr int BPG = 4;   // batches per gang

typedef _Float16 h2 __attribute__((ext_vector_type(2)));
typedef _Float16 h8 __attribute__((ext_vector_type(8)));
typedef float    f4 __attribute__((ext_vector_type(4)));
typedef unsigned int u32;
typedef u32 u32x2 __attribute__((ext_vector_type(2)));
typedef u32 u32x4 __attribute__((ext_vector_type(4)));

__device__ __forceinline__ float dot8(h8 w, h8 x, float acc) {
  h2 w0 = {w[0], w[1]}, w1 = {w[2], w[3]}, w2 = {w[4], w[5]}, w3 = {w[6], w[7]};
  h2 x0 = {x[0], x[1]}, x1 = {x[2], x[3]}, x2 = {x[4], x[5]}, x3 = {x[6], x[7]};
  acc = __builtin_amdgcn_fdot2(x0, w0, acc, false);
  acc = __builtin_amdgcn_fdot2(x1, w1, acc, false);
  acc = __builtin_amdgcn_fdot2(x2, w2, acc, false);
  acc = __builtin_amdgcn_fdot2(x3, w3, acc, false);
  return acc;
}

__device__ __forceinline__ float sigf(float x) { return 1.f / (1.f + __expf(-x)); }

// WG ss owns units [32ss,32ss+32). Per-WG col c128 = gate*32+u (0..127);
// col-block cb = c128>>4 (one per wave); global col = gate*512 + ss*32 + u.

// ---- Wc = W1@W_ih (fp32) -> f16 B-frags; bias2 = b1@W_ih + b_lstm ---------
__global__ void k_wc(const float* __restrict__ W1, const float* __restrict__ Wih,
                     const float* __restrict__ b1, const float* __restrict__ bl,
                     _Float16* __restrict__ Wc4, float* __restrict__ bias2) {
  const int j = blockIdx.x;   // global gate col 0..2047
  const int i = threadIdx.x;  // k index 0..127
  __shared__ float col[Hh];
  __shared__ float part[128];
  for (int k = i; k < Hh; k += 128) col[k] = Wih[k * G4 + j];
  __syncthreads();
  float s = 0.f;
  for (int k = i; k < Hh; k += 128) s += b1[k] * col[k];
  part[i] = s;
  __syncthreads();
  if (i == 0) {
    float t = bl[j];
    for (int k = 0; k < 128; k++) t += part[k];
    bias2[j] = t;
  }
  float acc = 0.f;
  const float* w1r = W1 + i * Hh;
#pragma unroll 4
  for (int k = 0; k < Hh; k++) acc += w1r[k] * col[k];
  const int gate = j >> 9, r = j & 511, ss = r >> 5, u = r & 31;
  const int c128 = gate * 32 + u, cb = c128 >> 4, c = c128 & 15;
  const int lane = ((i >> 3) & 3) * 16 + c, ks4 = i >> 5, e = i & 7;
  Wc4[((ss * 8 + cb) * 4 + ks4) * 512 + lane * 8 + e] = (_Float16)acc;
}

// ---- W_hh (fp32 [512][2048]) -> f16 B-frags -------------------------------
__global__ void k_whh(const float* __restrict__ W, _Float16* __restrict__ W4) {
  const int id = blockIdx.x * 256 + threadIdx.x;  // < 131072
  const int lane = id & 63, ks = (id >> 6) & 15, cb = (id >> 10) & 7, ss = id >> 13;
  const int c = lane & 15, c128 = cb * 16 + c;
  const int gate = c128 >> 5, u = c128 & 31;
  const int colg = gate * 512 + ss * 32 + u;
  h8 o;
#pragma unroll
  for (int e = 0; e < 8; ++e)
    o[e] = (_Float16)W[(ks * 32 + (lane >> 4) * 8 + e) * G4 + colg];
  *(h8*)(W4 + ((ss * 8 + cb) * 16 + ks) * 512 + lane * 8) = o;
}

// ---- persistent scan: 256 WGs = 16 gangs of 16 ----------------------------
__global__ __launch_bounds__(512, 1) void k_scan(
    const float* __restrict__ x, const _Float16* __restrict__ Wc4,
    const float* __restrict__ bias2, const _Float16* __restrict__ Whh4,
    const float* __restrict__ Wo, const float* __restrict__ bo,
    float* __restrict__ out, char* __restrict__ hpub) {
  const int gid = blockIdx.x >> 4, ss = blockIdx.x & 15;
  const int tid = threadIdx.x;
  const int lane = tid & 63, wv = tid >> 6;
  const int l15 = lane & 15, l4 = lane >> 4;

  __shared__ __align__(16) char hls[2][16384];  // h [16 rows][512] f16, (row<<4) XOR swizzle
  __shared__ __align__(16) char xws[4096];      // x window [8 rows][128] f16 swizzled (rows 8-15 zero)
  __shared__ __align__(16) char wots[32768];    // Wo^T [32][512] f16 swizzled
  __shared__ float pre_s[2][2][4][4][33];       // [buf][tt][b][gate][u]
  __shared__ float gat_s[4][4][33];             // [b][gate][u]
  __shared__ float op_s[32][17];

  // ---- register weights: wave wv owns col-block cb = wv --------------------
  h8 bW[16], bC[4];
#pragma unroll
  for (int ks = 0; ks < 16; ++ks)
    bW[ks] = *(const h8*)(Whh4 + ((ss * 8 + wv) * 16 + ks) * 512 + lane * 8);
#pragma unroll
  for (int ks = 0; ks < 4; ++ks)
    bC[ks] = *(const h8*)(Wc4 + ((ss * 8 + wv) * 4 + ks) * 512 + lane * 8);

  const int b8 = tid >> 5, ml = tid & 31;  // cell role (tid<128): batch, unit
  const float bI = bias2[ss * 32 + ml],        bF = bias2[512 + ss * 32 + ml],
              bG = bias2[1024 + ss * 32 + ml], bO = bias2[1536 + ss * 32 + ml];
  const int nn = tid & 31, pp = tid >> 5;  // out-proj role
  const float bor = (tid < NS) ? bo[tid] : 0.f;

  // ---- init LDS: zero both hls buffers + xws, stage Wo^T -------------------
#pragma unroll
  for (int q = 0; q < 2; ++q) {
    u32x4 z = {0, 0, 0, 0};
    *(u32x4*)(hls[0] + (q * 512 + tid) * 16) = z;
    *(u32x4*)(hls[1] + (q * 512 + tid) * 16) = z;
  }
  if (tid < 256) { u32x4 z = {0, 0, 0, 0}; *(u32x4*)(xws + tid * 16) = z; }
  for (int it = tid; it < Hh * NS; it += 512) {
    int k = it >> 5, n = it & 31;
    *(_Float16*)(wots + n * 1024 + ((2 * k) ^ ((n & 7) << 4))) = (_Float16)Wo[k * NS + n];
  }
  float c_ = 0.f;

  auto stage_x = [&](int t0) {  // rows tt*4+b of [8][128] f16
    if (tid < 128) {
      const int row = tid >> 4, cc = tid & 15;
      const float* src = x + ((size_t)(gid * BPG + (row & 3)) * Tt + t0 + (row >> 2)) * Ii + cc * 8;
      f4 s0 = *(const f4*)src, s1 = *(const f4*)(src + 4);
      h8 v = {(_Float16)s0[0], (_Float16)s0[1], (_Float16)s0[2], (_Float16)s0[3],
              (_Float16)s1[0], (_Float16)s1[1], (_Float16)s1[2], (_Float16)s1[3]};
      *(h8*)(xws + row * 256 + ((cc * 16) ^ ((row & 7) << 4))) = v;
    }
  };
  auto do_pregate = [&](int buf) {  // wave wv: its 16 cols; C rows 0-7 used
    f4 pa = {0.f, 0.f, 0.f, 0.f};
#pragma unroll
    for (int ks = 0; ks < 4; ++ks) {
      const int row = l15;
      h8 a = *(const h8*)(xws + row * 256 + ((ks * 64 + l4 * 16) ^ ((row & 7) << 4)));
      pa = __builtin_amdgcn_mfma_f32_16x16x32_f16(a, bC[ks], pa, 0, 0, 0);
    }
    if (l4 < 2) {
      const int c128 = wv * 16 + l15, gam = c128 >> 5, u = c128 & 31;
#pragma unroll
      for (int e = 0; e < 4; ++e) {
        const int row = l4 * 4 + e;  // 0..7 = tt*4 + b
        pre_s[buf][row >> 2][row & 3][gam][u] = pa[e];
      }
    }
  };
  auto op_part = [&](const char* hb) {  // WGs ss<4: partials of h[row ss] @ Wo
    if (ss < BPG) {
      float acc = 0.f;
#pragma unroll
      for (int q = 0; q < 4; ++q) {
        h8 w_ = *(const h8*)(wots + nn * 1024 + ((pp * 64 + q * 16) ^ ((nn & 7) << 4)));
        h8 hv = *(const h8*)(hb + ss * 1024 + ((pp * 64 + q * 16) ^ (ss << 4)));
        acc = dot8(w_, hv, acc);
      }
      op_s[nn][pp] = acc;
    }
  };

  stage_x(0);
  __syncthreads();
  do_pregate(0);  // steps 0,1

  int cur = 0;
#pragma unroll 1
  for (int t = 0; t < Tt; ++t) {
    char* const hpg = hpub + gid * 16384 + (t & 1) * 8192;
    const char* const hc = hls[cur];
    char* const hn_ = hls[cur ^ 1];
    // ---- gate GEMM: wave wv computes its 16 cols, K=512 -------------------
    {
      f4 g0 = {0.f, 0.f, 0.f, 0.f}, g1 = {0.f, 0.f, 0.f, 0.f};
#pragma unroll
      for (int ks = 0; ks < 16; ++ks) {
        const int row = l15;
        h8 a = *(const h8*)(hc + row * 1024 + ((ks * 64 + l4 * 16) ^ (row << 4)));
        if (ks & 1) g1 = __builtin_amdgcn_mfma_f32_16x16x32_f16(a, bW[ks], g1, 0, 0, 0);
        else        g0 = __builtin_amdgcn_mfma_f32_16x16x32_f16(a, bW[ks], g0, 0, 0, 0);
      }
      if (l4 == 0) {
        const int c128 = wv * 16 + l15, gam = c128 >> 5, u = c128 & 31;
#pragma unroll
        for (int e = 0; e < 4; ++e) gat_s[e][gam][u] = g0[e] + g1[e];
      }
    }
    __syncthreads();  // B1: gat_s ready
    // ---- cell update + tagged-packet publish (no ack, no flag) ------------
    if (tid < 128) {
      const int ph = (t >> 1) & 1, tt = t & 1;
      float aI = gat_s[b8][0][ml] + pre_s[ph][tt][b8][0][ml] + bI;
      float aF = gat_s[b8][1][ml] + pre_s[ph][tt][b8][1][ml] + bF;
      float aG = gat_s[b8][2][ml] + pre_s[ph][tt][b8][2][ml] + bG;
      float aO = gat_s[b8][3][ml] + pre_s[ph][tt][b8][3][ml] + bO;
      float iv = sigf(aI), fv = sigf(aF), gv = __sinf(aG), ov = sigf(aO);
      c_ = fv * c_ + iv * gv;
      float hnv = ov * __sinf(c_);
      _Float16 hf = (_Float16)hnv;
      u32 pkt = (u32)__builtin_bit_cast(unsigned short, hf) | ((u32)(t + 1) << 16);
      u32* dst = (u32*)(hpg + ((size_t)(b8 * 512 + ss * 32 + ml)) * 4);
      asm volatile("global_store_dword %0, %1, off sc0 sc1" :: "v"(dst), "v"(pkt) : "memory");
    }
    // ---- shadow (no remote deps) -----------------------------------------
    if (!(t & 1)) { if (t <= 1020) stage_x(t + 2); }
    else if (t <= 1021) do_pregate(((t + 1) >> 1) & 1);
    if (t > 0) op_part(hc);  // partials for out[t-1] from h_{t-1}
    // ---- poll own 4 packets, restage into hls[cur^1] ----------------------
    {
      const u32* sp = (const u32*)(hpg + (size_t)tid * 16);
      const u32 want = (u32)(t + 1);
      u32x4 v;
      while (true) {
        asm volatile("global_load_dwordx4 %0, %1, off sc0 sc1\ns_waitcnt vmcnt(0)"
                     : "=v"(v) : "v"(sp) : "memory");
        if ((v[0] >> 16) == want && (v[1] >> 16) == want &&
            (v[2] >> 16) == want && (v[3] >> 16) == want) break;
      }
      __builtin_amdgcn_sched_barrier(0);
      u32x2 d = {(v[0] & 0xFFFFu) | (v[1] << 16), (v[2] & 0xFFFFu) | (v[3] << 16)};
      const int b = tid >> 7, k = tid & 127;
      *(u32x2*)(hn_ + b * 1024 + ((k * 8) ^ (b << 4))) = d;
    }
    __syncthreads();  // B3: hls[cur^1] = h_t; op_s ready
    if (t > 0 && ss < BPG && tid < NS) {
      float s_ = bor;
#pragma unroll
      for (int p = 0; p < 16; ++p) s_ += op_s[tid][p];
      out[((size_t)(gid * BPG + ss) * Tt + (t - 1)) * NS + tid] = s_;
    }
    cur ^= 1;
  }
  // epilogue: out[1023] from h_1023 = hls[cur]
  op_part(hls[cur]);
  __syncthreads();
  if (ss < BPG && tid < NS) {
    float s_ = bor;
#pragma unroll
    for (int p = 0; p < 16; ++p) s_ += op_s[tid][p];
    out[((size_t)(gid * BPG + ss) * Tt + 1023) * NS + tid] = s_;
  }
}

extern "C" void kernel_launch(void* const* d_in, const int* in_sizes, int n_in,
                              void* d_out, int out_size, void* d_ws, size_t ws_size,
                              hipStream_t stream) {
  const float* x   = (const float*)d_in[0];
  const float* W1  = (const float*)d_in[1];
  const float* b1  = (const float*)d_in[2];
  const float* Wih = (const float*)d_in[3];
  const float* Whh = (const float*)d_in[4];
  const float* bl  = (const float*)d_in[5];
  const float* Wo  = (const float*)d_in[6];
  const float* bo  = (const float*)d_in[7];
  float* out = (float*)d_out;

  char* ws = (char*)d_ws;
  _Float16* Wc4   = (_Float16*)(ws);            // 512 KB
  float*    bias2 = (float*)(ws + 524288);      // 8 KB
  _Float16* Whh4  = (_Float16*)(ws + 532480);   // 2 MB
  char*     hpub  = ws + 2629632;               // 256 KB (16 gangs x 2 slots x 8KB)

  (void)hipMemsetAsync(hpub, 0, 262144, stream);  // kill stale tags (replay safety)
  k_wc<<<G4, 128, 0, stream>>>(W1, Wih, b1, bl, Wc4, bias2);
  k_whh<<<512, 256, 0, stream>>>(Whh, Whh4);
  k_scan<<<256, 512, 0, stream>>>(x, Wc4, bias2, Whh4, Wo, bo, out, hpub);
}